// Round 12
// baseline (451.087 us; speedup 1.0000x reference)
//
#include <hip/hip_runtime.h>
#include <hip/hip_bf16.h>
#include <stdint.h>

#define MEM_DIM 128
#define MSG_DIM 256
#define KTOT    384          // MSG_DIM + MEM_DIM
#define BM      32           // update rows per block

typedef __attribute__((ext_vector_type(8))) __bf16 bf16x8;
typedef __attribute__((ext_vector_type(4))) float  f32x4;

union B8u { uint32_t u[4]; bf16x8 v; };

__device__ __forceinline__ uint32_t cvt_pk(float lo, float hi) {
    uint32_t r;
    asm("v_cvt_pk_bf16_f32 %0, %1, %2" : "=v"(r) : "v"(lo), "v"(hi));
    return r;
}

__device__ __forceinline__ bf16x8 load_cvt8(const float* __restrict__ p) {
    f32x4 a = *(const f32x4*)p;
    f32x4 b = *(const f32x4*)(p + 4);
    B8u r;
    r.u[0] = cvt_pk(a.x, a.y);
    r.u[1] = cvt_pk(a.z, a.w);
    r.u[2] = cvt_pk(b.x, b.y);
    r.u[3] = cvt_pk(b.z, b.w);
    return r.v;
}

// nontemporal variant: streamed-once data (msgs) must not evict L2 weights
__device__ __forceinline__ bf16x8 load_cvt8_nt(const float* __restrict__ p) {
    f32x4 a = __builtin_nontemporal_load((const f32x4*)p);
    f32x4 b = __builtin_nontemporal_load((const f32x4*)(p + 4));
    B8u r;
    r.u[0] = cvt_pk(a.x, a.y);
    r.u[1] = cvt_pk(a.z, a.w);
    r.u[2] = cvt_pk(b.x, b.y);
    r.u[3] = cvt_pk(b.z, b.w);
    return r.v;
}

__device__ __forceinline__ float sigm(float x) {
    return __builtin_amdgcn_rcpf(1.0f + __expf(-x));
}
__device__ __forceinline__ float tanh_fast(float x) {
    return 1.0f - 2.0f * __builtin_amdgcn_rcpf(1.0f + __expf(2.0f * x));
}

// -------------------------------------- init: weight bf16 convert + bm zero
__global__ void init_kernel(const float* __restrict__ wih,
                            const float* __restrict__ whh,
                            __hip_bfloat16* __restrict__ wb,
                            uint32_t* __restrict__ bm, int bmwords) {
    int i = blockIdx.x * 256 + threadIdx.x;
    const int NIH = 3 * MEM_DIM * MSG_DIM;   // 98304
    const int NHH = 3 * MEM_DIM * MEM_DIM;   // 49152
    if (i < NIH)            wb[i] = __float2bfloat16(wih[i]);
    else if (i < NIH + NHH) wb[i] = __float2bfloat16(whh[i - NIH]);
    if (i < bmwords) bm[i] = 0;
}
__global__ void bm_set_kernel(const int* __restrict__ ids, uint32_t* __restrict__ bm, int U) {
    int i = blockIdx.x * 256 + threadIdx.x;
    if (i < U) {
        int id = ids[i];
        atomicOr(&bm[id >> 5], 1u << (id & 31));
    }
}

// ----------------------------------------------- copy kernel (skips updated)
__global__ void copy_skip_kernel(const f32x4* __restrict__ mem,
                                 const float* __restrict__ lu,
                                 f32x4* __restrict__ outm,
                                 float* __restrict__ outlu,
                                 const uint32_t* __restrict__ bm,
                                 int NN) {
    const int64_t n_mem_chunks = (int64_t)NN * 32;   // 512 B rows / 16 B
    const int64_t total = n_mem_chunks + NN;
    const int64_t stride = (int64_t)gridDim.x * blockDim.x;
    for (int64_t i = (int64_t)blockIdx.x * blockDim.x + threadIdx.x; i < total; i += stride) {
        if (i < n_mem_chunks) {
            int row = (int)(i >> 5);
            if (!((bm[row >> 5] >> (row & 31)) & 1u)) {
                f32x4 v = __builtin_nontemporal_load(&mem[i]);
                __builtin_nontemporal_store(v, &outm[i]);
            }
        } else {
            int node = (int)(i - n_mem_chunks);
            if (!((bm[node >> 5] >> (node & 31)) & 1u))
                outlu[node] = lu[node];
        }
    }
}

// fallback full copy (no workspace for bitmap)
__global__ void copy_all_kernel(const f32x4* __restrict__ mem,
                                const f32x4* __restrict__ lu,
                                f32x4* __restrict__ out,
                                int n_mem4, int n_tot4) {
    int stride = gridDim.x * blockDim.x;
    for (int i = blockIdx.x * blockDim.x + threadIdx.x; i < n_tot4; i += stride) {
        f32x4 v = (i < n_mem4) ? mem[i]
                               : __builtin_nontemporal_load(&lu[i - n_mem4]);
        __builtin_nontemporal_store(v, &out[i]);
    }
}

// ---------------------------------------------------------------- stream GRU
// BM=32, 512 threads = 8 waves; wave w owns output cols w*16..w*16+15 and
// computes 2 M-tiles (32 rows). acc = 32 regs/lane -> ~90-reg footprint ->
// 5-6 waves/SIMD, ~3 independent blocks/CU (vs 2 at BM=64): more concurrent
// HBM streams. hv (blend h_old) read from GLOBAL, issued right after the
// barrier so it stays in flight across the whole k-loop. msgs loads NT.
__device__ __forceinline__ int at_addr(int row, int kbyte) {
    return (row * (KTOT * 2) + kbyte) ^ ((row & 7) << 4);
}

template<bool PRE>
__global__ __launch_bounds__(512)
void gru32_kernel(const float* __restrict__ memory,
                  const int*   __restrict__ ids,
                  const float* __restrict__ msgs,
                  const float* __restrict__ ts,
                  const float* __restrict__ Wih,
                  const float* __restrict__ Whh,
                  const float* __restrict__ bih,
                  const float* __restrict__ bhh,
                  const __hip_bfloat16* __restrict__ WihB,  // [384][256]
                  const __hip_bfloat16* __restrict__ WhhB,  // [384][128]
                  float* __restrict__ out_mem,
                  float* __restrict__ out_lu,
                  int U) {
    __shared__ __align__(16) char At[BM * KTOT * 2];   // 24576 B

    const int tid  = threadIdx.x;
    const int w    = tid >> 6;
    const int lane = tid & 63;
    const int lq   = lane & 15;
    const int lk   = lane >> 4;
    const int rb   = blockIdx.x * BM;

    // ---- timestamp scatter
    if (tid < BM) {
        int r = rb + tid;
        if (r < U) out_lu[ids[r]] = ts[r];
    }

    // ---- stage At: x part (512 threads, 32B bf16 out per thread)
    {
        int r = tid >> 4, seg = tid & 15;
        int rA = rb + r; if (rA >= U) rA = U - 1;
        const float* xp = msgs + (size_t)rA * MSG_DIM + seg * 16;
        *(bf16x8*)(At + at_addr(r, seg * 32))      = load_cvt8_nt(xp);
        *(bf16x8*)(At + at_addr(r, seg * 32 + 16)) = load_cvt8_nt(xp + 8);
    }
    // ---- stage At: h part (512 threads, 16B bf16 out per thread)
    {
        int r = tid >> 4, u = tid & 15;
        int rA = rb + r; if (rA >= U) rA = U - 1;
        const float* hp = memory + (size_t)ids[rA] * MEM_DIM + u * 8;
        *(bf16x8*)(At + at_addr(r, 512 + u * 16)) = load_cvt8(hp);
    }

    // this lane's output column + biases
    const int c = w * 16 + lq;
    const float br  = bih[c] + bhh[c];
    const float bz  = bih[MEM_DIM + c] + bhh[MEM_DIM + c];
    const float bin = bih[2 * MEM_DIM + c];
    const float bhn = bhh[2 * MEM_DIM + c];

    // per-lane weight base pointers
    const __hip_bfloat16* wih_l = WihB + c * MSG_DIM + lk * 8;
    const __hip_bfloat16* whh_l = WhhB + c * MEM_DIM + lk * 8;
    const float* wih_f = Wih + c * MSG_DIM + lk * 8;
    const float* whh_f = Whh + c * MEM_DIM + lk * 8;

    const f32x4 z4 = {0.f, 0.f, 0.f, 0.f};
    f32x4 acc[2][4];
    #pragma unroll
    for (int m = 0; m < 2; ++m)
        #pragma unroll
        for (int q = 0; q < 4; ++q) acc[m][q] = z4;

    __syncthreads();   // At ready

    // hv / oid: issued NOW so the loads stay in flight across the k-loop
    int   oid[2][4];
    float hv[2][4];
    #pragma unroll
    for (int m = 0; m < 2; ++m)
        #pragma unroll
        for (int j = 0; j < 4; ++j) {
            int r = rb + m * 16 + lk * 4 + j;
            oid[m][j] = ids[(r < U) ? r : (U - 1)];
            hv[m][j]  = memory[(size_t)oid[m][j] * MEM_DIM + c];
        }

    // ---------------- phase X: W_ih, 8 k-steps, gates r,z,i_n
    #pragma unroll 1
    for (int ks = 0; ks < 8; ++ks) {
        bf16x8 bv0, bv1, bv2;
        if (PRE) {
            bv0 = *(const bf16x8*)(wih_l + 0 * 128 * MSG_DIM + ks * 32);
            bv1 = *(const bf16x8*)(wih_l + 1 * 128 * MSG_DIM + ks * 32);
            bv2 = *(const bf16x8*)(wih_l + 2 * 128 * MSG_DIM + ks * 32);
        } else {
            bv0 = load_cvt8(wih_f + 0 * 128 * MSG_DIM + ks * 32);
            bv1 = load_cvt8(wih_f + 1 * 128 * MSG_DIM + ks * 32);
            bv2 = load_cvt8(wih_f + 2 * 128 * MSG_DIM + ks * 32);
        }
        bf16x8 af[2];
        #pragma unroll
        for (int m = 0; m < 2; ++m)
            af[m] = *(const bf16x8*)(At + at_addr(m * 16 + lq, ks * 64 + lk * 16));
        #pragma unroll
        for (int m = 0; m < 2; ++m)
            acc[m][0] = __builtin_amdgcn_mfma_f32_16x16x32_bf16(af[m], bv0, acc[m][0], 0, 0, 0);
        #pragma unroll
        for (int m = 0; m < 2; ++m)
            acc[m][1] = __builtin_amdgcn_mfma_f32_16x16x32_bf16(af[m], bv1, acc[m][1], 0, 0, 0);
        #pragma unroll
        for (int m = 0; m < 2; ++m)
            acc[m][2] = __builtin_amdgcn_mfma_f32_16x16x32_bf16(af[m], bv2, acc[m][2], 0, 0, 0);
    }
    // ---------------- phase H: W_hh, 4 k-steps, gates r,z,h_n
    #pragma unroll 1
    for (int ks = 0; ks < 4; ++ks) {
        bf16x8 bv0, bv1, bv2;
        if (PRE) {
            bv0 = *(const bf16x8*)(whh_l + 0 * 128 * MEM_DIM + ks * 32);
            bv1 = *(const bf16x8*)(whh_l + 1 * 128 * MEM_DIM + ks * 32);
            bv2 = *(const bf16x8*)(whh_l + 2 * 128 * MEM_DIM + ks * 32);
        } else {
            bv0 = load_cvt8(whh_f + 0 * 128 * MEM_DIM + ks * 32);
            bv1 = load_cvt8(whh_f + 1 * 128 * MEM_DIM + ks * 32);
            bv2 = load_cvt8(whh_f + 2 * 128 * MEM_DIM + ks * 32);
        }
        bf16x8 af[2];
        #pragma unroll
        for (int m = 0; m < 2; ++m)
            af[m] = *(const bf16x8*)(At + at_addr(m * 16 + lq, 512 + ks * 64 + lk * 16));
        #pragma unroll
        for (int m = 0; m < 2; ++m)
            acc[m][0] = __builtin_amdgcn_mfma_f32_16x16x32_bf16(af[m], bv0, acc[m][0], 0, 0, 0);
        #pragma unroll
        for (int m = 0; m < 2; ++m)
            acc[m][1] = __builtin_amdgcn_mfma_f32_16x16x32_bf16(af[m], bv1, acc[m][1], 0, 0, 0);
        #pragma unroll
        for (int m = 0; m < 2; ++m)
            acc[m][3] = __builtin_amdgcn_mfma_f32_16x16x32_bf16(af[m], bv2, acc[m][3], 0, 0, 0);
    }

    // ---- epilogue: gate math + NT scatter (h_old from registers)
    #pragma unroll
    for (int m = 0; m < 2; ++m) {
        #pragma unroll
        for (int j = 0; j < 4; ++j) {
            int r = rb + m * 16 + lk * 4 + j;
            if (r < U) {
                float rg = sigm(acc[m][0][j] + br);
                float zg = sigm(acc[m][1][j] + bz);
                float ng = tanh_fast(acc[m][2][j] + bin + rg * (acc[m][3][j] + bhn));
                __builtin_nontemporal_store(
                    (1.0f - zg) * ng + zg * hv[m][j],
                    &out_mem[(size_t)oid[m][j] * MEM_DIM + c]);
            }
        }
    }
}

// ------------------------------------------------------------------- launcher
extern "C" void kernel_launch(void* const* d_in, const int* in_sizes, int n_in,
                              void* d_out, int out_size, void* d_ws, size_t ws_size,
                              hipStream_t stream) {
    const float* memory      = (const float*)d_in[0];
    const float* last_update = (const float*)d_in[1];
    const int*   ids         = (const int*)  d_in[2];
    const float* msgs        = (const float*)d_in[3];
    const float* ts          = (const float*)d_in[4];
    const float* Wih         = (const float*)d_in[5];
    const float* Whh         = (const float*)d_in[6];
    const float* bih         = (const float*)d_in[7];
    const float* bhh         = (const float*)d_in[8];

    const int NN = in_sizes[1];          // 1,000,000 nodes
    const int U  = in_sizes[2];          // 200,000 updates

    float* out_mem = (float*)d_out;
    float* out_lu  = out_mem + (size_t)NN * MEM_DIM;

    const int NIH = 3 * MEM_DIM * MSG_DIM;                    // 98304
    const int NHH = 3 * MEM_DIM * MEM_DIM;                    // 49152
    const size_t WBYTES  = (size_t)(NIH + NHH) * sizeof(__hip_bfloat16);  // 294912
    const size_t BM_OFF  = (WBYTES + 255) & ~(size_t)255;
    const int    BMWORDS = (NN + 31) / 32;
    const int    nblocks = (U + BM - 1) / BM;                 // 6250

    if (ws_size >= BM_OFF + (size_t)BMWORDS * 4) {
        __hip_bfloat16* wb = (__hip_bfloat16*)d_ws;
        uint32_t* bm = (uint32_t*)((char*)d_ws + BM_OFF);

        int initn = (NIH + NHH > BMWORDS) ? (NIH + NHH) : BMWORDS;
        init_kernel<<<(initn + 255) / 256, 256, 0, stream>>>(Wih, Whh, wb, bm, BMWORDS);
        bm_set_kernel<<<(U + 255) / 256, 256, 0, stream>>>(ids, bm, U);

        gru32_kernel<true><<<nblocks, 512, 0, stream>>>(
            memory, ids, msgs, ts, Wih, Whh, bih, bhh,
            wb, wb + NIH, out_mem, out_lu, U);

        copy_skip_kernel<<<8192, 256, 0, stream>>>((const f32x4*)memory, last_update,
                                                   (f32x4*)out_mem, out_lu, bm, NN);
    } else {
        int n_mem4 = NN * MEM_DIM / 4;
        int n_tot4 = n_mem4 + NN / 4;
        copy_all_kernel<<<8192, 256, 0, stream>>>((const f32x4*)memory,
                                                  (const f32x4*)last_update,
                                                  (f32x4*)d_out, n_mem4, n_tot4);
        gru32_kernel<false><<<nblocks, 512, 0, stream>>>(
            memory, ids, msgs, ts, Wih, Whh, bih, bhh,
            nullptr, nullptr, out_mem, out_lu, U);
    }
}

// Round 13
// 400.885 us; speedup vs baseline: 1.1252x; 1.1252x over previous
//
#include <hip/hip_runtime.h>
#include <hip/hip_bf16.h>
#include <stdint.h>

#define MEM_DIM 128
#define MSG_DIM 256
#define KTOT    384          // MSG_DIM + MEM_DIM
#define BM      64           // update rows per block

typedef __attribute__((ext_vector_type(8))) __bf16 bf16x8;
typedef __attribute__((ext_vector_type(4))) float  f32x4;

union B8u { uint32_t u[4]; bf16x8 v; };

__device__ __forceinline__ uint32_t cvt_pk(float lo, float hi) {
    uint32_t r;
    asm("v_cvt_pk_bf16_f32 %0, %1, %2" : "=v"(r) : "v"(lo), "v"(hi));
    return r;
}

__device__ __forceinline__ bf16x8 load_cvt8(const float* __restrict__ p) {
    f32x4 a = *(const f32x4*)p;
    f32x4 b = *(const f32x4*)(p + 4);
    B8u r;
    r.u[0] = cvt_pk(a.x, a.y);
    r.u[1] = cvt_pk(a.z, a.w);
    r.u[2] = cvt_pk(b.x, b.y);
    r.u[3] = cvt_pk(b.z, b.w);
    return r.v;
}

__device__ __forceinline__ float sigm(float x) {
    return __builtin_amdgcn_rcpf(1.0f + __expf(-x));
}
__device__ __forceinline__ float tanh_fast(float x) {
    return 1.0f - 2.0f * __builtin_amdgcn_rcpf(1.0f + __expf(2.0f * x));
}

// ----------------------- init: pack weights into fragment order + bm zero
// Packed layout: X-part = 8ks x 3g x 8w groups of 1KB (64 lanes x 16B);
// H-part (offset 98304 elems) = 4ks x 3g x 8w groups. Within a group,
// lane l (lq=l&15, lk=l>>4) holds W[g*128 + w*16 + lq][ks*32 + lk*8 .. +7].
__global__ void init_kernel(const float* __restrict__ wih,
                            const float* __restrict__ whh,
                            __hip_bfloat16* __restrict__ wp,
                            uint32_t* __restrict__ bm, int bmwords) {
    int u = blockIdx.x * 256 + threadIdx.x;
    const int XU = 8 * 3 * 8 * 64;          // 12288 units (bf16x8 each)
    const int HU = 4 * 3 * 8 * 64;          // 6144 units
    if (u < XU) {
        int group = u >> 6, lane = u & 63;
        int ks = group / 24, g = (group % 24) >> 3, w = group & 7;
        int lq = lane & 15, lk = lane >> 4;
        const float* src = wih + (size_t)(g * 128 + w * 16 + lq) * MSG_DIM + ks * 32 + lk * 8;
        __hip_bfloat16* dst = wp + (size_t)u * 8;
        #pragma unroll
        for (int i = 0; i < 8; ++i) dst[i] = __float2bfloat16(src[i]);
    } else if (u < XU + HU) {
        int v = u - XU;
        int group = v >> 6, lane = v & 63;
        int ks = group / 24, g = (group % 24) >> 3, w = group & 7;
        int lq = lane & 15, lk = lane >> 4;
        const float* src = whh + (size_t)(g * 128 + w * 16 + lq) * MEM_DIM + ks * 32 + lk * 8;
        __hip_bfloat16* dst = wp + (size_t)(XU + v) * 8;
        #pragma unroll
        for (int i = 0; i < 8; ++i) dst[i] = __float2bfloat16(src[i]);
    }
    if (u < bmwords) bm[u] = 0;
}
__global__ void bm_set_kernel(const int* __restrict__ ids, uint32_t* __restrict__ bm, int U) {
    int i = blockIdx.x * 256 + threadIdx.x;
    if (i < U) {
        int id = ids[i];
        atomicOr(&bm[id >> 5], 1u << (id & 31));
    }
}

// ----------------------------------------------- copy kernel (skips updated)
__global__ void copy_skip_kernel(const f32x4* __restrict__ mem,
                                 const float* __restrict__ lu,
                                 f32x4* __restrict__ outm,
                                 float* __restrict__ outlu,
                                 const uint32_t* __restrict__ bm,
                                 int NN) {
    const int64_t n_mem_chunks = (int64_t)NN * 32;   // 512 B rows / 16 B
    const int64_t total = n_mem_chunks + NN;
    const int64_t stride = (int64_t)gridDim.x * blockDim.x;
    for (int64_t i = (int64_t)blockIdx.x * blockDim.x + threadIdx.x; i < total; i += stride) {
        if (i < n_mem_chunks) {
            int row = (int)(i >> 5);
            if (!((bm[row >> 5] >> (row & 31)) & 1u)) {
                f32x4 v = __builtin_nontemporal_load(&mem[i]);
                __builtin_nontemporal_store(v, &outm[i]);
            }
        } else {
            int node = (int)(i - n_mem_chunks);
            if (!((bm[node >> 5] >> (node & 31)) & 1u))
                outlu[node] = lu[node];
        }
    }
}

// fallback full copy (no workspace for bitmap)
__global__ void copy_all_kernel(const f32x4* __restrict__ mem,
                                const f32x4* __restrict__ lu,
                                f32x4* __restrict__ out,
                                int n_mem4, int n_tot4) {
    int stride = gridDim.x * blockDim.x;
    for (int i = blockIdx.x * blockDim.x + threadIdx.x; i < n_tot4; i += stride) {
        f32x4 v = (i < n_mem4) ? mem[i]
                               : __builtin_nontemporal_load(&lu[i - n_mem4]);
        __builtin_nontemporal_store(v, &out[i]);
    }
}

// ---------------------------------------------------------------- stream GRU
// R8 structure (BM=64, 8 waves, At LDS, B streamed global->MFMA) with B loads
// COALESCED via the packed fragment layout: each (ks,gate,w) group is a
// contiguous 1KB block; lane l reads base + l*16 -> 1 transaction/load
// (was 16). hv/oid from global, issued post-barrier (in flight over k-loop).
__device__ __forceinline__ int at_addr(int row, int kbyte) {
    return (row * (KTOT * 2) + kbyte) ^ ((row & 7) << 4);
}

template<bool PRE>
__global__ __launch_bounds__(512, 4)
void gru_stream_kernel(const float* __restrict__ memory,
                       const int*   __restrict__ ids,
                       const float* __restrict__ msgs,
                       const float* __restrict__ ts,
                       const float* __restrict__ Wih,
                       const float* __restrict__ Whh,
                       const float* __restrict__ bih,
                       const float* __restrict__ bhh,
                       const __hip_bfloat16* __restrict__ WP,   // packed frags
                       float* __restrict__ out_mem,
                       float* __restrict__ out_lu,
                       int U) {
    __shared__ __align__(16) char At[BM * KTOT * 2];   // 49152 B

    const int tid  = threadIdx.x;
    const int w    = tid >> 6;
    const int lane = tid & 63;
    const int lq   = lane & 15;
    const int lk   = lane >> 4;
    const int rb   = blockIdx.x * BM;

    // ---- timestamp scatter
    if (tid < BM) {
        int r = rb + tid;
        if (r < U) out_lu[ids[r]] = ts[r];
    }

    // ---- stage At: x part (512 threads, 8 segs of 32 f32 per row)
    {
        int r = tid >> 3, seg = tid & 7;
        int rA = rb + r; if (rA >= U) rA = U - 1;
        const float* xp = msgs + (size_t)rA * MSG_DIM + seg * 32;
        #pragma unroll
        for (int i = 0; i < 4; ++i)
            *(bf16x8*)(At + at_addr(r, seg * 64 + i * 16)) = load_cvt8(xp + i * 8);
    }
    // ---- stage At: h part (512 threads, 8 units of 16 f32 per row)
    {
        int r = tid >> 3, u = tid & 7;
        int rA = rb + r; if (rA >= U) rA = U - 1;
        const float* hp = memory + (size_t)ids[rA] * MEM_DIM + u * 16;
        *(bf16x8*)(At + at_addr(r, 512 + u * 32))      = load_cvt8(hp);
        *(bf16x8*)(At + at_addr(r, 512 + u * 32 + 16)) = load_cvt8(hp + 8);
    }

    // this lane's output column + biases
    const int c = w * 16 + lq;
    const float br  = bih[c] + bhh[c];
    const float bz  = bih[MEM_DIM + c] + bhh[MEM_DIM + c];
    const float bin = bih[2 * MEM_DIM + c];
    const float bhn = bhh[2 * MEM_DIM + c];

    // packed-fragment base for this lane (X part; groups are ks*24+g*8+w)
    const __hip_bfloat16* wpx = WP + (size_t)w * 512 + lane * 8;
    const __hip_bfloat16* wph = WP + (size_t)(8 * 3 * 8 * 64) * 8 + (size_t)w * 512 + lane * 8;
    // fallback (f32 direct) base pointers
    const float* wih_f = Wih + c * MSG_DIM + lk * 8;
    const float* whh_f = Whh + c * MEM_DIM + lk * 8;

    const f32x4 z4 = {0.f, 0.f, 0.f, 0.f};
    f32x4 acc[4][4];
    #pragma unroll
    for (int m = 0; m < 4; ++m)
        #pragma unroll
        for (int q = 0; q < 4; ++q) acc[m][q] = z4;

    __syncthreads();   // At ready

    // hv / oid from global: issued NOW, in flight across the whole k-loop
    int   oid[4];
    float hv[4];
    #pragma unroll
    for (int j = 0; j < 4; ++j) {
        int r = rb + (lk << 2) + j;      // row group base; m-tile offset added later
        (void)r;
    }
    int   oidm[4][4];
    float hvm[4][4];
    #pragma unroll
    for (int m = 0; m < 4; ++m)
        #pragma unroll
        for (int j = 0; j < 4; ++j) {
            int r = rb + m * 16 + lk * 4 + j;
            oidm[m][j] = ids[(r < U) ? r : (U - 1)];
            hvm[m][j]  = memory[(size_t)oidm[m][j] * MEM_DIM + c];
        }

    // ---------------- phase X: W_ih, 8 k-steps, gates r,z,i_n
    #pragma unroll 1
    for (int ks = 0; ks < 8; ++ks) {
        bf16x8 bv0, bv1, bv2;
        if (PRE) {
            const __hip_bfloat16* p = wpx + (size_t)ks * 24 * 512;
            bv0 = *(const bf16x8*)(p);
            bv1 = *(const bf16x8*)(p + 8 * 512);
            bv2 = *(const bf16x8*)(p + 16 * 512);
        } else {
            bv0 = load_cvt8(wih_f + 0 * 128 * MSG_DIM + ks * 32);
            bv1 = load_cvt8(wih_f + 1 * 128 * MSG_DIM + ks * 32);
            bv2 = load_cvt8(wih_f + 2 * 128 * MSG_DIM + ks * 32);
        }
        bf16x8 af[4];
        #pragma unroll
        for (int m = 0; m < 4; ++m)
            af[m] = *(const bf16x8*)(At + at_addr(m * 16 + lq, ks * 64 + lk * 16));
        #pragma unroll
        for (int m = 0; m < 4; ++m)
            acc[m][0] = __builtin_amdgcn_mfma_f32_16x16x32_bf16(af[m], bv0, acc[m][0], 0, 0, 0);
        #pragma unroll
        for (int m = 0; m < 4; ++m)
            acc[m][1] = __builtin_amdgcn_mfma_f32_16x16x32_bf16(af[m], bv1, acc[m][1], 0, 0, 0);
        #pragma unroll
        for (int m = 0; m < 4; ++m)
            acc[m][2] = __builtin_amdgcn_mfma_f32_16x16x32_bf16(af[m], bv2, acc[m][2], 0, 0, 0);
    }
    // ---------------- phase H: W_hh, 4 k-steps, gates r,z,h_n
    #pragma unroll 1
    for (int ks = 0; ks < 4; ++ks) {
        bf16x8 bv0, bv1, bv2;
        if (PRE) {
            const __hip_bfloat16* p = wph + (size_t)ks * 24 * 512;
            bv0 = *(const bf16x8*)(p);
            bv1 = *(const bf16x8*)(p + 8 * 512);
            bv2 = *(const bf16x8*)(p + 16 * 512);
        } else {
            bv0 = load_cvt8(whh_f + 0 * 128 * MEM_DIM + ks * 32);
            bv1 = load_cvt8(whh_f + 1 * 128 * MEM_DIM + ks * 32);
            bv2 = load_cvt8(whh_f + 2 * 128 * MEM_DIM + ks * 32);
        }
        bf16x8 af[4];
        #pragma unroll
        for (int m = 0; m < 4; ++m)
            af[m] = *(const bf16x8*)(At + at_addr(m * 16 + lq, 512 + ks * 64 + lk * 16));
        #pragma unroll
        for (int m = 0; m < 4; ++m)
            acc[m][0] = __builtin_amdgcn_mfma_f32_16x16x32_bf16(af[m], bv0, acc[m][0], 0, 0, 0);
        #pragma unroll
        for (int m = 0; m < 4; ++m)
            acc[m][1] = __builtin_amdgcn_mfma_f32_16x16x32_bf16(af[m], bv1, acc[m][1], 0, 0, 0);
        #pragma unroll
        for (int m = 0; m < 4; ++m)
            acc[m][3] = __builtin_amdgcn_mfma_f32_16x16x32_bf16(af[m], bv2, acc[m][3], 0, 0, 0);
    }

    // ---- epilogue: gate math + scatter (h_old from registers)
    #pragma unroll
    for (int m = 0; m < 4; ++m) {
        #pragma unroll
        for (int j = 0; j < 4; ++j) {
            int r = rb + m * 16 + lk * 4 + j;
            if (r < U) {
                float rg = sigm(acc[m][0][j] + br);
                float zg = sigm(acc[m][1][j] + bz);
                float ng = tanh_fast(acc[m][2][j] + bin + rg * (acc[m][3][j] + bhn));
                __builtin_nontemporal_store(
                    (1.0f - zg) * ng + zg * hvm[m][j],
                    &out_mem[(size_t)oidm[m][j] * MEM_DIM + c]);
            }
        }
    }
}

// ------------------------------------------------------------------- launcher
extern "C" void kernel_launch(void* const* d_in, const int* in_sizes, int n_in,
                              void* d_out, int out_size, void* d_ws, size_t ws_size,
                              hipStream_t stream) {
    const float* memory      = (const float*)d_in[0];
    const float* last_update = (const float*)d_in[1];
    const int*   ids         = (const int*)  d_in[2];
    const float* msgs        = (const float*)d_in[3];
    const float* ts          = (const float*)d_in[4];
    const float* Wih         = (const float*)d_in[5];
    const float* Whh         = (const float*)d_in[6];
    const float* bih         = (const float*)d_in[7];
    const float* bhh         = (const float*)d_in[8];

    const int NN = in_sizes[1];          // 1,000,000 nodes
    const int U  = in_sizes[2];          // 200,000 updates

    float* out_mem = (float*)d_out;
    float* out_lu  = out_mem + (size_t)NN * MEM_DIM;

    const int NIH = 3 * MEM_DIM * MSG_DIM;                    // 98304
    const int NHH = 3 * MEM_DIM * MEM_DIM;                    // 49152
    const size_t WBYTES  = (size_t)(NIH + NHH) * sizeof(__hip_bfloat16);  // 294912
    const size_t BM_OFF  = (WBYTES + 255) & ~(size_t)255;
    const int    BMWORDS = (NN + 31) / 32;
    const int    nblocks = (U + BM - 1) / BM;                 // 3125

    if (ws_size >= BM_OFF + (size_t)BMWORDS * 4) {
        __hip_bfloat16* wp = (__hip_bfloat16*)d_ws;
        uint32_t* bm = (uint32_t*)((char*)d_ws + BM_OFF);

        int initn = ((NIH + NHH) / 8 > BMWORDS) ? (NIH + NHH) / 8 : BMWORDS;
        init_kernel<<<(initn + 255) / 256, 256, 0, stream>>>(Wih, Whh, wp, bm, BMWORDS);
        bm_set_kernel<<<(U + 255) / 256, 256, 0, stream>>>(ids, bm, U);

        gru_stream_kernel<true><<<nblocks, 512, 0, stream>>>(
            memory, ids, msgs, ts, Wih, Whh, bih, bhh,
            wp, out_mem, out_lu, U);

        copy_skip_kernel<<<8192, 256, 0, stream>>>((const f32x4*)memory, last_update,
                                                   (f32x4*)out_mem, out_lu, bm, NN);
    } else {
        int n_mem4 = NN * MEM_DIM / 4;
        int n_tot4 = n_mem4 + NN / 4;
        copy_all_kernel<<<8192, 256, 0, stream>>>((const f32x4*)memory,
                                                  (const f32x4*)last_update,
                                                  (f32x4*)d_out, n_mem4, n_tot4);
        gru_stream_kernel<false><<<nblocks, 512, 0, stream>>>(
            memory, ids, msgs, ts, Wih, Whh, bih, bhh,
            nullptr, out_mem, out_lu, U);
    }
}